// Round 1
// 434.647 us; speedup vs baseline: 1.0867x; 1.0867x over previous
//
#include <hip/hip_runtime.h>

#define NNODE 100
#define HDIM  128
#define NEDGE 360
#define NT    512

typedef float f32x4 __attribute__((ext_vector_type(4)));
typedef short s16x8 __attribute__((ext_vector_type(8)));

__device__ __forceinline__ float bf2f(short s) {
  union { unsigned int u; float f; } v;
  v.u = ((unsigned int)(unsigned short)s) << 16;
  return v.f;
}
__device__ __forceinline__ short f2bf(float f) {  // RNE
  union { float f; unsigned int u; } v; v.f = f;
  unsigned int u = v.u + 0x7fffu + ((v.u >> 16) & 1u);
  return (short)(u >> 16);
}
// XOR-swizzled LDS index (shorts). Row stride 128 shorts (256B); 16B groups
// permuted by row&15 so stride-256B row accesses spread across all banks.
__device__ __forceinline__ int sidx(int r, int k) {
  return (r << 7) + ((((k >> 3) ^ (r & 15)) << 3) | (k & 7));
}

// ---------------- prep 1: weight transposes (bf16 [n][k]) + incoming-edge lists ----
// wt slots (16384 shorts each): 0=W1, 1=Wc(=W2@Wu1b, filled by prep_fold),
//                               2=Wu1a, 3=Wu2
__global__ __launch_bounds__(NT)
void prep_tr(const float* __restrict__ w_msg1, const float* __restrict__ w_upd1,
             const float* __restrict__ w_upd2, const int* __restrict__ dst_idx,
             short* __restrict__ wt, int* __restrict__ inl) {
  int idx = blockIdx.x * NT + threadIdx.x;
  if (idx < 3 * 16384) {
    int m = idx >> 14, i = idx & 16383;
    int n = i >> 7, k = i & 127;
    const float* W = (m == 0) ? w_msg1 : (m == 1) ? w_upd1 : w_upd2;
    int slot = (m == 0) ? 0 : (m == 1) ? 2 : 3;
    wt[slot * 16384 + n * HDIM + k] = f2bf(W[k * HDIM + n]);
  }
  if (blockIdx.x == 0) {
    __shared__ int cnt[NNODE];
    int tid = threadIdx.x;
    if (tid < NNODE) cnt[tid] = 0;
    __syncthreads();
    if (tid < NEDGE) {
      int d = dst_idx[tid];
      int p = atomicAdd(&cnt[d], 1);
      inl[d * 4 + p] = tid;
    }
    __syncthreads();
    if (tid < NNODE) {
      for (int p = cnt[tid]; p < 4; ++p) inl[tid * 4 + p] = -1;
    }
  }
}

// ---------------- prep 2: fold GEMM2 into upd1.  Wc = W2 @ Wu1b,  bv = b2 @ Wu1b
// block i<128 computes Wc row i (threads j coalesced over Wu1b rows);
// block 128 computes bv.
__global__ __launch_bounds__(128)
void prep_fold(const float* __restrict__ w_msg2, const float* __restrict__ w_upd1,
               const float* __restrict__ b_msg2,
               short* __restrict__ wt, float* __restrict__ bv) {
  const int j = threadIdx.x;
  if (blockIdx.x < 128) {
    const int i = blockIdx.x;
    float s = 0.f;
#pragma unroll 4
    for (int k = 0; k < 128; ++k)
      s += w_msg2[i * HDIM + k] * w_upd1[(HDIM + k) * HDIM + j];
    wt[16384 + j * HDIM + i] = f2bf(s);   // B-layout: [n=j][k=i]
  } else {
    float s = 0.f;
#pragma unroll 4
    for (int k = 0; k < 128; ++k)
      s += b_msg2[k] * w_upd1[(HDIM + k) * HDIM + j];
    bv[j] = s;
  }
}

// ---------------- main fused kernel: one block per batch element, 67.6 KB LDS ----
// Phases: stage(x->buf0 bf16) | P1 t=x@W1 ->buf1 | P2 magg gather ->buf0 |
//         B1 u1=relu(magg@Wc + x@Wu1a + bu1 + cnt*bv) ->buf1 |
//         B2 h=u1@Wu2+bu2+x, LN via cross-wave partial sums, direct global store.
__global__ __launch_bounds__(NT, 4)
void mpnn_main(const float* __restrict__ x,
               const int* __restrict__ src_idx,
               const float* __restrict__ edge_dir,
               const float* __restrict__ w_msg1,   // row 128 = edge-feature column
               const float* __restrict__ b_msg1,
               const float* __restrict__ b_upd1,
               const float* __restrict__ b_upd2,
               const float* __restrict__ gamma,
               const float* __restrict__ beta,
               const short* __restrict__ wt,
               const float* __restrict__ bv_g,
               const int* __restrict__ inl_g,
               float* __restrict__ out)
{
  __shared__ __align__(16) char smem[69184];
  short* buf0 = (short*)smem;             // 25600 B: xls, then magg
  short* buf1 = (short*)(smem + 25600);   // 32768 B: t (128 rows), then u1
  float* lnb  = (float*)(smem + 58368);   // 2048 B: per-(row,wc) {s1,s2}
  int*   srcl = (int*)(smem + 60416);     // 1536
  float* eds  = (float*)(smem + 61952);   // 1536
  int*   inls = (int*)(smem + 63488);     // 1600
  float* cntf = (float*)(smem + 65088);   // 512 (rows 100..127 = 0)
  float* b1s  = (float*)(smem + 65600);
  float* w1ls = (float*)(smem + 66112);
  float* bvs  = (float*)(smem + 66624);
  float* bu1s = (float*)(smem + 67136);
  float* bu2s = (float*)(smem + 67648);
  float* gms  = (float*)(smem + 68160);
  float* bts  = (float*)(smem + 68672);

  const int tid  = threadIdx.x;
  const int lane = tid & 63;
  const int wave = tid >> 6;
  const int quad = lane >> 4;
  const int l16  = lane & 15;
  const int wr   = wave >> 1;   // 0..3  row group (32 rows)
  const int wc   = wave & 1;    // 0..1  col half (64 cols)
  const int b    = blockIdx.x;
  const float* xb = x + (size_t)b * (NNODE * HDIM);

  s16x8 wf[4][4];   // B-fragments [ct][kq]
  auto loadB = [&](const short* w) {
#pragma unroll
    for (int ct = 0; ct < 4; ++ct)
#pragma unroll
      for (int kq = 0; kq < 4; ++kq)
        wf[ct][kq] = *(const s16x8*)&w[(wc * 64 + ct * 16 + l16) * HDIM + kq * 32 + quad * 8];
  };

  // ---- staging ----
  loadB(wt);   // W1
  for (int G = tid; G < NNODE * 16; G += NT) {
    int r = G >> 4, g = G & 15;
    const float4* p = (const float4*)(xb + r * HDIM + g * 8);
    float4 v0 = p[0], v1 = p[1];
    s16x8 h;
    h[0] = f2bf(v0.x); h[1] = f2bf(v0.y); h[2] = f2bf(v0.z); h[3] = f2bf(v0.w);
    h[4] = f2bf(v1.x); h[5] = f2bf(v1.y); h[6] = f2bf(v1.z); h[7] = f2bf(v1.w);
    *(s16x8*)&buf0[sidx(r, g * 8)] = h;
  }
  if (tid < 384) {
    srcl[tid] = (tid < NEDGE) ? src_idx[tid] : 0;
    eds[tid]  = (tid < NEDGE) ? edge_dir[tid] : 0.f;
  }
  if (tid < NNODE) {
    int4 il = ((const int4*)inl_g)[tid];
    ((int4*)inls)[tid] = il;
    cntf[tid] = (float)((il.x >= 0) + (il.y >= 0) + (il.z >= 0) + (il.w >= 0));
  } else if (tid < HDIM) {
    cntf[tid] = 0.f;
  }
  if (tid < HDIM) {
    b1s[tid]  = b_msg1[tid];
    w1ls[tid] = w_msg1[HDIM * HDIM + tid];
    bvs[tid]  = bv_g[tid];
    bu1s[tid] = b_upd1[tid];
    bu2s[tid] = b_upd2[tid];
    gms[tid]  = gamma[tid];
    bts[tid]  = beta[tid];
  }
  __syncthreads();

  const int r0 = wr * 32 + l16;
  const int r1 = r0 + 16;
  const int m0 = (r0 < NNODE) ? r0 : 0;   // clamp garbage rows (outputs discarded)
  const int m1 = (r1 < NNODE) ? r1 : 0;

  // ---- P1: t = x @ W1 (per-NODE, replaces per-edge GEMM1) ----
  {
    f32x4 acc[2][4] = {};
#pragma unroll
    for (int kq = 0; kq < 4; ++kq) {
      const int ko = kq * 32 + quad * 8;
      s16x8 a0 = *(const s16x8*)&buf0[sidx(m0, ko)];
      s16x8 a1 = *(const s16x8*)&buf0[sidx(m1, ko)];
#pragma unroll
      for (int ct = 0; ct < 4; ++ct) {
        acc[0][ct] = __builtin_amdgcn_mfma_f32_16x16x32_bf16(a0, wf[ct][kq], acc[0][ct], 0, 0, 0);
        acc[1][ct] = __builtin_amdgcn_mfma_f32_16x16x32_bf16(a1, wf[ct][kq], acc[1][ct], 0, 0, 0);
      }
    }
    loadB(wt + 16384);   // Wc; latency hides over epilogue+barrier+P2
#pragma unroll
    for (int rt = 0; rt < 2; ++rt)
#pragma unroll
      for (int i = 0; i < 4; ++i) {
        const int row = wr * 32 + rt * 16 + quad * 4 + i;
#pragma unroll
        for (int ct = 0; ct < 4; ++ct) {
          const int col = wc * 64 + ct * 16 + l16;
          buf1[sidx(row, col)] = f2bf(acc[rt][ct][i]);
        }
      }
  }
  __syncthreads();

  // ---- P2: magg[v] = sum_{e into v} relu(t[src[e]] + b1 + ed[e]*w1L) -> buf0 ----
  for (int G = tid; G < NNODE * 16; G += NT) {
    const int v = G >> 4, ko = (G & 15) * 8;
    const int4 il = ((const int4*)inls)[v];
    const float4 ba = *(const float4*)&b1s[ko];
    const float4 bb = *(const float4*)&b1s[ko + 4];
    const float4 wa = *(const float4*)&w1ls[ko];
    const float4 wb = *(const float4*)&w1ls[ko + 4];
    float s[8] = {0, 0, 0, 0, 0, 0, 0, 0};
    const int es[4] = {il.x, il.y, il.z, il.w};
#pragma unroll
    for (int j = 0; j < 4; ++j) {
      if (es[j] >= 0) {
        const int e = es[j];
        const float ed = eds[e];
        s16x8 t8 = *(const s16x8*)&buf1[sidx(srcl[e], ko)];
        float u;
        u = bf2f(t8[0]) + ba.x + ed * wa.x; s[0] += u > 0.f ? u : 0.f;
        u = bf2f(t8[1]) + ba.y + ed * wa.y; s[1] += u > 0.f ? u : 0.f;
        u = bf2f(t8[2]) + ba.z + ed * wa.z; s[2] += u > 0.f ? u : 0.f;
        u = bf2f(t8[3]) + ba.w + ed * wa.w; s[3] += u > 0.f ? u : 0.f;
        u = bf2f(t8[4]) + bb.x + ed * wb.x; s[4] += u > 0.f ? u : 0.f;
        u = bf2f(t8[5]) + bb.y + ed * wb.y; s[5] += u > 0.f ? u : 0.f;
        u = bf2f(t8[6]) + bb.z + ed * wb.z; s[6] += u > 0.f ? u : 0.f;
        u = bf2f(t8[7]) + bb.w + ed * wb.w; s[7] += u > 0.f ? u : 0.f;
      }
    }
    s16x8 o;
#pragma unroll
    for (int t = 0; t < 8; ++t) o[t] = f2bf(s[t]);
    *(s16x8*)&buf0[sidx(v, ko)] = o;
  }
  __syncthreads();

  // ---- B1: u1 = relu(magg @ Wc + x @ Wu1a + bu1 + cnt*bv) -> buf1 ----
  // (agg@Wu1b folded: agg = magg@W2 + cnt*b2  =>  magg@(W2@Wu1b) + cnt*(b2@Wu1b))
  {
    f32x4 acc[2][4] = {};
#pragma unroll
    for (int kq = 0; kq < 4; ++kq) {
      const int ko = kq * 32 + quad * 8;
      s16x8 a0 = *(const s16x8*)&buf0[sidx(m0, ko)];
      s16x8 a1 = *(const s16x8*)&buf0[sidx(m1, ko)];
#pragma unroll
      for (int ct = 0; ct < 4; ++ct) {
        acc[0][ct] = __builtin_amdgcn_mfma_f32_16x16x32_bf16(a0, wf[ct][kq], acc[0][ct], 0, 0, 0);
        acc[1][ct] = __builtin_amdgcn_mfma_f32_16x16x32_bf16(a1, wf[ct][kq], acc[1][ct], 0, 0, 0);
      }
    }
    loadB(wt + 2 * 16384);   // Wu1a
    // x-half: A-fragments straight from global (L2-hot; frees xls so LDS fits 2 blocks/CU)
#pragma unroll
    for (int kq = 0; kq < 4; ++kq) {
      const int ko = kq * 32 + quad * 8;
#pragma unroll
      for (int rt = 0; rt < 2; ++rt) {
        const int rr = rt ? m1 : m0;
        const float4* p = (const float4*)(xb + rr * HDIM + ko);
        float4 v0 = p[0], v1 = p[1];
        s16x8 a;
        a[0] = f2bf(v0.x); a[1] = f2bf(v0.y); a[2] = f2bf(v0.z); a[3] = f2bf(v0.w);
        a[4] = f2bf(v1.x); a[5] = f2bf(v1.y); a[6] = f2bf(v1.z); a[7] = f2bf(v1.w);
#pragma unroll
        for (int ct = 0; ct < 4; ++ct)
          acc[rt][ct] = __builtin_amdgcn_mfma_f32_16x16x32_bf16(a, wf[ct][kq], acc[rt][ct], 0, 0, 0);
      }
    }
    loadB(wt + 3 * 16384);   // Wu2; latency overlaps epilogue+barrier
#pragma unroll
    for (int rt = 0; rt < 2; ++rt)
#pragma unroll
      for (int i = 0; i < 4; ++i) {
        const int row = wr * 32 + rt * 16 + quad * 4 + i;
        const float cn = cntf[row];
#pragma unroll
        for (int ct = 0; ct < 4; ++ct) {
          const int col = wc * 64 + ct * 16 + l16;
          float v = acc[rt][ct][i] + bu1s[col] + cn * bvs[col];
          buf1[sidx(row, col)] = f2bf(v > 0.f ? v : 0.f);
        }
      }
  }
  __syncthreads();

  // ---- B2: h = u1 @ Wu2 + bu2 + x; LayerNorm via cross-wave partial sums ----
  {
    f32x4 acc[2][4] = {};
#pragma unroll
    for (int kq = 0; kq < 4; ++kq) {
      const int ko = kq * 32 + quad * 8;
      s16x8 a0 = *(const s16x8*)&buf1[sidx(wr * 32 + l16, ko)];
      s16x8 a1 = *(const s16x8*)&buf1[sidx(wr * 32 + 16 + l16, ko)];
#pragma unroll
      for (int ct = 0; ct < 4; ++ct) {
        acc[0][ct] = __builtin_amdgcn_mfma_f32_16x16x32_bf16(a0, wf[ct][kq], acc[0][ct], 0, 0, 0);
        acc[1][ct] = __builtin_amdgcn_mfma_f32_16x16x32_bf16(a1, wf[ct][kq], acc[1][ct], 0, 0, 0);
      }
    }
#pragma unroll
    for (int rt = 0; rt < 2; ++rt)
#pragma unroll
      for (int i = 0; i < 4; ++i) {
        const int row = wr * 32 + rt * 16 + quad * 4 + i;
        if (row < NNODE) {
          float s1 = 0.f, s2 = 0.f;
#pragma unroll
          for (int ct = 0; ct < 4; ++ct) {
            const int col = wc * 64 + ct * 16 + l16;
            const float h = acc[rt][ct][i] + bu2s[col] + xb[row * HDIM + col];
            acc[rt][ct][i] = h;
            s1 += h; s2 += h * h;
          }
          // reduce this row's 64-col partials across the 16 lanes that hold it
#pragma unroll
          for (int off = 8; off > 0; off >>= 1) {
            s1 += __shfl_xor(s1, off, 64);
            s2 += __shfl_xor(s2, off, 64);
          }
          if (l16 == 0) { lnb[(row * 2 + wc) * 2] = s1; lnb[(row * 2 + wc) * 2 + 1] = s2; }
        }
      }
    __syncthreads();
#pragma unroll
    for (int rt = 0; rt < 2; ++rt)
#pragma unroll
      for (int i = 0; i < 4; ++i) {
        const int row = wr * 32 + rt * 16 + quad * 4 + i;
        if (row < NNODE) {
          const float s1 = lnb[row * 4] + lnb[row * 4 + 2];
          const float s2 = lnb[row * 4 + 1] + lnb[row * 4 + 3];
          const float mu  = s1 * (1.0f / HDIM);
          const float var = s2 * (1.0f / HDIM) - mu * mu;
          const float rs  = rsqrtf(var + 1e-5f);
#pragma unroll
          for (int ct = 0; ct < 4; ++ct) {
            const int col = wc * 64 + ct * 16 + l16;
            out[((size_t)b * NNODE + row) * HDIM + col] =
                (acc[rt][ct][i] - mu) * rs * gms[col] + bts[col];
          }
        }
      }
  }
}

extern "C" void kernel_launch(void* const* d_in, const int* in_sizes, int n_in,
                              void* d_out, int out_size, void* d_ws, size_t ws_size,
                              hipStream_t stream) {
  const float* x      = (const float*)d_in[0];
  const int*   src    = (const int*)  d_in[1];
  const int*   dst    = (const int*)  d_in[2];
  const float* ed     = (const float*)d_in[3];
  const float* w_msg1 = (const float*)d_in[4];
  const float* b_msg1 = (const float*)d_in[5];
  const float* w_msg2 = (const float*)d_in[6];
  const float* b_msg2 = (const float*)d_in[7];
  const float* w_upd1 = (const float*)d_in[8];
  const float* b_upd1 = (const float*)d_in[9];
  const float* w_upd2 = (const float*)d_in[10];
  const float* b_upd2 = (const float*)d_in[11];
  const float* gamma  = (const float*)d_in[12];
  const float* beta   = (const float*)d_in[13];
  float* out = (float*)d_out;

  short* wt  = (short*)d_ws;                      // 4 * 32768 B (W1, Wc, Wu1a, Wu2)
  float* bv  = (float*)((char*)d_ws + 131072);    // 512 B
  int*   inl = (int*)((char*)d_ws + 131584);      // 100 * int4

  prep_tr<<<96, NT, 0, stream>>>(w_msg1, w_upd1, w_upd2, dst, wt, inl);
  prep_fold<<<129, 128, 0, stream>>>(w_msg2, w_upd1, b_msg2, wt, bv);

  const int Bsz = in_sizes[0] / (NNODE * HDIM);   // 2048
  mpnn_main<<<Bsz, NT, 0, stream>>>(x, src, ed, w_msg1, b_msg1,
                                    b_upd1, b_upd2, gamma, beta, wt, bv, inl, out);
}